// Round 4
// baseline (122.491 us; speedup 1.0000x reference)
//
#include <hip/hip_runtime.h>

// Problem constants (fixed by reference)
#define NB 8
#define NN 2048
#define KK 64
#define VV 64
#define SCALE 0.18033688011112043f  // (1/sqrt(64)) * log2(e)

typedef __bf16 bfrag  __attribute__((ext_vector_type(8)));
typedef __bf16 bf16x4 __attribute__((ext_vector_type(4)));
typedef float  f32x4  __attribute__((ext_vector_type(4)));

// LDS byte offset, 256B rows, XOR-swizzled (G4: kills the stride-256B
// 16-row bank conflict on ds_read_b128 column-ish access)
__device__ __forceinline__ int swz256(int row, int colByte) {
  return row * 256 + (colByte ^ ((row & 7) << 4));
}

__device__ __forceinline__ bfrag lds_frag(const unsigned short* base, int row, int colByte) {
  return *reinterpret_cast<const bfrag*>(
      reinterpret_cast<const char*>(base) + swz256(row, colByte));
}

// 8 consecutive global fp32 -> bf16 MFMA fragment.
// Plain (__bf16) casts -> compiler emits v_cvt_pk_bf16_f32 (2 elem/inst).
__device__ __forceinline__ bfrag g_frag(const float* __restrict__ g) {
  const float4* p = reinterpret_cast<const float4*>(g);
  float4 x = p[0], y = p[1];
  bfrag r;
  r[0] = (__bf16)x.x; r[1] = (__bf16)x.y; r[2] = (__bf16)x.z; r[3] = (__bf16)x.w;
  r[4] = (__bf16)y.x; r[5] = (__bf16)y.y; r[6] = (__bf16)y.z; r[7] = (__bf16)y.w;
  return r;
}

// ---- V staging: rows (il, il+1) x 8 v -> transposed Vt[v][i] ----
struct VS { float4 f[4]; };
__device__ __forceinline__ void v_load(VS& s, const float* __restrict__ g) {
  const float4* p = reinterpret_cast<const float4*>(g);
  s.f[0] = p[0]; s.f[1] = p[1];
  const float4* q = reinterpret_cast<const float4*>(g + VV);
  s.f[2] = q[0]; s.f[3] = q[1];
}
__device__ __forceinline__ void v_write(const VS& s, unsigned short* lds, int il, int v0) {
  const float* lo = reinterpret_cast<const float*>(&s.f[0]);
  const float* hi = reinterpret_cast<const float*>(&s.f[2]);
#pragma unroll
  for (int j = 0; j < 8; ++j) {
    __bf16 two[2] = { (__bf16)lo[j], (__bf16)hi[j] };
    *reinterpret_cast<unsigned*>(reinterpret_cast<char*>(lds) + swz256(v0 + j, il * 2)) =
        *reinterpret_cast<unsigned*>(two);
  }
}

// =====================================================================
// K_D: partial softmax denominators. grid 1024 = (b, ot64, ci512).
// Direct-global K/Q fragments, NO LDS tiles, no loop barriers.
// Also zeroes the U accumulator (values region of d_out).
// =====================================================================
__global__ void __launch_bounds__(256) attn_denom(
    const float* __restrict__ key, const float* __restrict__ query,
    float* __restrict__ dpart, float* __restrict__ uzero)
{
  __shared__ float Red[4][64];

  const int tid  = threadIdx.x;
  const int lane = tid & 63;
  const int wv   = tid >> 6;
  const int l15  = lane & 15;
  const int l4   = lane >> 4;

  const int b    = blockIdx.x & 7;          // batch -> XCD
  const int rest = blockIdx.x >> 3;
  const int ot   = rest & 31;               // o-tile (64)
  const int ci   = rest >> 5;               // i-chunk (512)

  const float* Kg = key   + (size_t)b * NN * KK;
  const float* Qg = query + (size_t)b * NN * KK;

  // zero U region: 1024 blocks x 256 threads x 16B = 4MB
  {
    float4 z4 = {0.f, 0.f, 0.f, 0.f};
    reinterpret_cast<float4*>(uzero)[(size_t)blockIdx.x * 256 + tid] = z4;
  }

  // Q fragments (B-op: row o = l15, k = l4*8+j), direct from global
  bfrag qb[4][2];
#pragma unroll
  for (int s = 0; s < 4; ++s) {
    const float* qr = Qg + (size_t)(ot * 64 + s * 16 + l15) * KK;
    qb[s][0] = g_frag(qr + l4 * 8);
    qb[s][1] = g_frag(qr + 32 + l4 * 8);
  }

  float Dacc[4] = {0.f, 0.f, 0.f, 0.f};
  const int ib0 = ci * 512;
  for (int t = 0; t < 8; ++t) {
    const float* kr = Kg + (size_t)(ib0 + t * 64 + wv * 16 + l15) * KK;
    bfrag a0 = g_frag(kr + l4 * 8);
    bfrag a1 = g_frag(kr + 32 + l4 * 8);
#pragma unroll
    for (int s = 0; s < 4; ++s) {
      f32x4 z = {0.f, 0.f, 0.f, 0.f};
      z = __builtin_amdgcn_mfma_f32_16x16x32_bf16(a0, qb[s][0], z, 0, 0, 0);
      z = __builtin_amdgcn_mfma_f32_16x16x32_bf16(a1, qb[s][1], z, 0, 0, 0);
      Dacc[s] += exp2f(z[0] * SCALE) + exp2f(z[1] * SCALE) +
                 exp2f(z[2] * SCALE) + exp2f(z[3] * SCALE);
    }
  }

#pragma unroll
  for (int s = 0; s < 4; ++s) {
    float d = Dacc[s];
    d += __shfl_xor(d, 16, 64);
    d += __shfl_xor(d, 32, 64);
    if (lane < 16) Red[wv][s * 16 + lane] = d;
  }
  __syncthreads();
  if (tid < 64)
    dpart[(size_t)((b * 32 + ot) * 4 + ci) * 64 + tid] =
        Red[0][tid] + Red[1][tid] + Red[2][tid] + Red[3][tid];
}

// =====================================================================
// K_W: main tile kernel. grid 2048 = (b, it128, ot128), one 128x128
// score tile per block. Writes weights (134MB), accumulates U atomically.
// 2 barriers total, no i-loop. LDS: Vt 16K + Et 32K + InvD -> 3 blk/CU.
// =====================================================================
__global__ void __launch_bounds__(256) attn_main(
    const float* __restrict__ key, const float* __restrict__ query,
    const float* __restrict__ value, const float* __restrict__ dpart,
    float* __restrict__ U, float* __restrict__ Wout)
{
  __shared__ __align__(16) unsigned short Vt[64 * 128];    // [v][i*2B], 256B rows
  __shared__ __align__(16) unsigned short Et[128 * 128];   // [o][i*2B], 256B rows
  __shared__ float InvD[128];

  const int tid  = threadIdx.x;
  const int lane = tid & 63;
  const int wv   = tid >> 6;
  const int l15  = lane & 15;
  const int l4   = lane >> 4;

  const int b    = blockIdx.x & 7;           // batch -> XCD
  const int rest = blockIdx.x >> 3;
  const int it   = rest & 15;                // i-tile (128)
  const int ot   = rest >> 4;                // o-tile (128)

  const float* Kg = key   + (size_t)b * NN * KK;
  const float* Qg = query + (size_t)b * NN * KK;
  const float* Vg = value + (size_t)b * NN * VV;
  float* outW = Wout + (size_t)b * NN * NN;

  // issue V loads early (consumed after barrier 2's producer side)
  const int vil = (tid & 63) * 2;            // i-row pair within tile
  const int vv0 = (tid >> 6) * 8;            // v group
  VS vs0, vs1;
  v_load(vs0, Vg + (size_t)(it * 128 + vil) * VV + vv0);
  v_load(vs1, Vg + (size_t)(it * 128 + vil) * VV + vv0 + 32);

  // gather invD for this block's 128 o's
  if (tid < 128) {
    const int otile = ot * 2 + (tid >> 6);
    const float* dp = dpart + (size_t)((b * 32 + otile) * 4) * 64 + (tid & 63);
    InvD[tid] = 1.f / (dp[0] + dp[64] + dp[128] + dp[192]);
  }
  __syncthreads();   // barrier 1: InvD ready
  float invd[8];
#pragma unroll
  for (int s = 0; s < 8; ++s) invd[s] = InvD[s * 16 + l15];

  // K fragments (A-op, wave i-strip = wv*32) and Q fragments (B-op), direct global
  bfrag aK[2][2], qb[8][2];
#pragma unroll
  for (int m = 0; m < 2; ++m) {
    const float* kr = Kg + (size_t)(it * 128 + wv * 32 + m * 16 + l15) * KK;
    aK[m][0] = g_frag(kr + l4 * 8);
    aK[m][1] = g_frag(kr + 32 + l4 * 8);
  }
#pragma unroll
  for (int s = 0; s < 8; ++s) {
    const float* qr = Qg + (size_t)(ot * 128 + s * 16 + l15) * KK;
    qb[s][0] = g_frag(qr + l4 * 8);
    qb[s][1] = g_frag(qr + 32 + l4 * 8);
  }

  // S = K.Q^T ; E = exp ; store weights ; stash E (bf16) into Et
#pragma unroll
  for (int m = 0; m < 2; ++m) {
#pragma unroll
    for (int s = 0; s < 8; ++s) {
      f32x4 z = {0.f, 0.f, 0.f, 0.f};
      z = __builtin_amdgcn_mfma_f32_16x16x32_bf16(aK[m][0], qb[s][0], z, 0, 0, 0);
      z = __builtin_amdgcn_mfma_f32_16x16x32_bf16(aK[m][1], qb[s][1], z, 0, 0, 0);
      f32x4 e;
#pragma unroll
      for (int r = 0; r < 4; ++r) e[r] = exp2f(z[r] * SCALE);
      // weights[i][o]: i = it*128 + wv*32 + m*16 + l4*4 + r, o = ot*128 + s*16 + l15
      float* wp = outW + (size_t)(it * 128 + wv * 32 + m * 16 + l4 * 4) * NN +
                  ot * 128 + s * 16 + l15;
      const float iv = invd[s];
#pragma unroll
      for (int r = 0; r < 4; ++r) wp[(size_t)r * NN] = e[r] * iv;
      // Et[o][i] (bf16): row o = s*16+l15, i = wv*32 + m*16 + l4*4 + {0..3}
      bf16x4 pk;
#pragma unroll
      for (int r = 0; r < 4; ++r) pk[r] = (__bf16)e[r];
      *reinterpret_cast<bf16x4*>(reinterpret_cast<char*>(Et) +
          swz256(s * 16 + l15, (wv * 32 + m * 16 + l4 * 4) * 2)) = pk;
    }
  }
  // V -> Vt (transposed, bf16)
  v_write(vs0, Vt, vil, vv0);
  v_write(vs1, Vt, vil, vv0 + 32);
  __syncthreads();   // barrier 2: Et + Vt ready

  // PV: U[v][o] += V^T.E over this tile's 128 i. Wave owns v-strip wv*16.
  bfrag va[4];
#pragma unroll
  for (int kh = 0; kh < 4; ++kh)
    va[kh] = lds_frag(Vt, wv * 16 + l15, kh * 64 + l4 * 16);
#pragma unroll
  for (int s = 0; s < 8; ++s) {
    f32x4 z = {0.f, 0.f, 0.f, 0.f};
#pragma unroll
    for (int kh = 0; kh < 4; ++kh) {
      bfrag eb = lds_frag(Et, s * 16 + l15, kh * 64 + l4 * 16);
      z = __builtin_amdgcn_mfma_f32_16x16x32_bf16(va[kh], eb, z, 0, 0, 0);
    }
    // lane: v = wv*16 + l4*4 + r, o = ot*128 + s*16 + l15
    float* up = U + (size_t)b * VV * NN + (size_t)(wv * 16 + l4 * 4) * NN +
                ot * 128 + s * 16 + l15;
#pragma unroll
    for (int r = 0; r < 4; ++r)
      unsafeAtomicAdd(up + (size_t)r * NN, z[r]);
  }
}

// =====================================================================
// K_F: in-place column L2-normalize of U -> values. grid 256 = (b, oc64).
// =====================================================================
__global__ void __launch_bounds__(256) attn_norm(float* __restrict__ out)
{
  __shared__ float Ut[64][65];
  __shared__ float Sc[64];

  const int tid = threadIdx.x;
  const int b   = blockIdx.x & 7;
  const int oc  = blockIdx.x >> 3;
  float* base = out + (size_t)b * VV * NN + oc * 64;

  const int v  = tid >> 2;
  const int oq = (tid & 3) * 16;

  float x[16];
#pragma unroll
  for (int j = 0; j < 4; ++j) {
    float4 f = *reinterpret_cast<const float4*>(base + (size_t)v * NN + oq + j * 4);
    x[j * 4 + 0] = f.x; x[j * 4 + 1] = f.y; x[j * 4 + 2] = f.z; x[j * 4 + 3] = f.w;
  }
#pragma unroll
  for (int k = 0; k < 16; ++k) Ut[v][oq + k] = x[k];
  __syncthreads();
  if (tid < 64) {
    float ssq = 0.f;
#pragma unroll
    for (int vv = 0; vv < 64; ++vv) ssq += Ut[vv][tid] * Ut[vv][tid];
    Sc[tid] = 1.f / (sqrtf(ssq) + 1e-12f);
  }
  __syncthreads();
#pragma unroll
  for (int j = 0; j < 4; ++j) {
    float4 f;
    f.x = x[j * 4 + 0] * Sc[oq + j * 4 + 0];
    f.y = x[j * 4 + 1] * Sc[oq + j * 4 + 1];
    f.z = x[j * 4 + 2] * Sc[oq + j * 4 + 2];
    f.w = x[j * 4 + 3] * Sc[oq + j * 4 + 3];
    *reinterpret_cast<float4*>(base + (size_t)v * NN + oq + j * 4) = f;
  }
}

extern "C" void kernel_launch(void* const* d_in, const int* in_sizes, int n_in,
                              void* d_out, int out_size, void* d_ws, size_t ws_size,
                              hipStream_t stream) {
  (void)in_sizes; (void)n_in; (void)ws_size; (void)out_size;
  const float* key   = (const float*)d_in[0];
  const float* query = (const float*)d_in[1];
  const float* value = (const float*)d_in[2];
  float* out   = (float*)d_out;
  float* U     = out;                              // values region doubles as U accumulator
  float* Wgt   = out + (size_t)NB * VV * NN;       // [B][N][N] weights
  float* dpart = (float*)d_ws;                     // 1024*64 floats = 256 KB

  attn_denom<<<dim3(NB * 32 * 4), dim3(256), 0, stream>>>(key, query, dpart, U);
  attn_main <<<dim3(NB * 16 * 16), dim3(256), 0, stream>>>(key, query, value, dpart, U, Wgt);
  attn_norm <<<dim3(NB * 32),      dim3(256), 0, stream>>>(out);
}

// Round 5
// 88.840 us; speedup vs baseline: 1.3788x; 1.3788x over previous
//
#include <hip/hip_runtime.h>

// Problem constants (fixed by reference)
#define NB 8
#define NN 2048
#define KK 64
#define VV 64
#define SCALE 0.18033688011112043f  // (1/sqrt(64)) * log2(e)

typedef __bf16 bfrag  __attribute__((ext_vector_type(8)));
typedef __bf16 bf16x4 __attribute__((ext_vector_type(4)));
typedef float  f32x4  __attribute__((ext_vector_type(4)));

// LDS byte offset within a tile with 128B rows, XOR-swizzled (G4)
__device__ __forceinline__ int swz(int row, int colByte) {
  return row * 128 + (colByte ^ ((row & 7) << 4));
}

__device__ __forceinline__ bfrag lds_frag(const unsigned short* base, int row, int colByte) {
  return *reinterpret_cast<const bfrag*>(reinterpret_cast<const char*>(base) + swz(row, colByte));
}

// 8 consecutive global fp32 -> bf16 MFMA fragment (v_cvt_pk via plain casts)
__device__ __forceinline__ bfrag g_frag(const float* __restrict__ g) {
  const float4* p = reinterpret_cast<const float4*>(g);
  float4 x = p[0], y = p[1];
  bfrag r;
  r[0] = (__bf16)x.x; r[1] = (__bf16)x.y; r[2] = (__bf16)x.z; r[3] = (__bf16)x.w;
  r[4] = (__bf16)y.x; r[5] = (__bf16)y.y; r[6] = (__bf16)y.z; r[7] = (__bf16)y.w;
  return r;
}

// ---- staging: 16 consecutive fp32 -> 16 bf16 into one LDS row ----
struct KS { float4 f[4]; };
__device__ __forceinline__ void k_load(KS& s, const float* __restrict__ g) {
  const float4* p = reinterpret_cast<const float4*>(g);
  s.f[0] = p[0]; s.f[1] = p[1]; s.f[2] = p[2]; s.f[3] = p[3];
}
__device__ __forceinline__ void k_write(const KS& s, unsigned short* lds, int row, int colByte) {
  const float* f = reinterpret_cast<const float*>(&s.f[0]);
  bfrag a, b;
#pragma unroll
  for (int j = 0; j < 8; ++j) a[j] = (__bf16)f[j];
#pragma unroll
  for (int j = 0; j < 8; ++j) b[j] = (__bf16)f[8 + j];
  *reinterpret_cast<bfrag*>(reinterpret_cast<char*>(lds) + swz(row, colByte)) = a;
  *reinterpret_cast<bfrag*>(reinterpret_cast<char*>(lds) + swz(row, colByte + 16)) = b;
}

// ---- V staging: rows (il, il+1) x 8 v -> transposed Vt[v][i] ----
struct VS { float4 f[4]; };
__device__ __forceinline__ void v_load(VS& s, const float* __restrict__ g) {
  const float4* p = reinterpret_cast<const float4*>(g);
  s.f[0] = p[0]; s.f[1] = p[1];
  const float4* q = reinterpret_cast<const float4*>(g + VV);
  s.f[2] = q[0]; s.f[3] = q[1];
}
__device__ __forceinline__ void v_write(const VS& s, unsigned short* lds, int il, int v0) {
  const float* lo = reinterpret_cast<const float*>(&s.f[0]);
  const float* hi = reinterpret_cast<const float*>(&s.f[2]);
#pragma unroll
  for (int j = 0; j < 8; ++j) {
    __bf16 two[2] = { (__bf16)lo[j], (__bf16)hi[j] };
    *reinterpret_cast<unsigned*>(reinterpret_cast<char*>(lds) + swz(v0 + j, il * 2)) =
        *reinterpret_cast<unsigned*>(two);
  }
}

// =====================================================================
// K1: per (b, o-tile 64, i-chunk 512): partial D[64] + partial U[64][64]
// -> scratch. Q fragments hoisted to registers (direct global); K/V
// single-buffered LDS, 2 barriers/step.
// =====================================================================
#define CHUNK 512
#define IT 64
#define K1STEPS (CHUNK / IT)   // 8
#define SCR_STRIDE 4160        // 64*64 U + 64 D floats per chunk

__global__ void __launch_bounds__(256) attn_pass1(
    const float* __restrict__ key, const float* __restrict__ query,
    const float* __restrict__ value, float* __restrict__ scratch)
{
  __shared__ __align__(16) unsigned short Kt[IT * KK];
  __shared__ __align__(16) unsigned short Vt[VV * IT];
  __shared__ __align__(16) unsigned short Et[64 * IT];
  __shared__ float Red[4][64];

  const int tid  = threadIdx.x;
  const int lane = tid & 63;
  const int wv   = tid >> 6;
  const int l15  = lane & 15;
  const int l4   = lane >> 4;

  const int b    = blockIdx.x & 7;          // batch -> XCD
  const int rest = blockIdx.x >> 3;
  const int ot   = rest & 31;               // o-tile (64)
  const int ci   = rest >> 5;               // i-chunk (512)
  const int o0   = ot * 64;
  const int ib0  = ci * CHUNK;

  const float* Kg = key   + (size_t)b * NN * KK;
  const float* Qg = query + (size_t)b * NN * KK;
  const float* Vg = value + (size_t)b * NN * VV;
  float* scr = scratch + (size_t)((b * 32 + ot) * 4 + ci) * SCR_STRIDE;

  const int krow = tid >> 2;          // 0..63
  const int kel  = (tid & 3) * 16;
  const int kcb  = (tid & 3) * 32;
  const int vil  = (tid & 31) * 2;
  const int vv0  = (tid >> 5) * 8;

  // Q fragments (B-op: o = l15, k = l4*8+j), direct from global
  bfrag qb0[4], qb1[4];
#pragma unroll
  for (int s = 0; s < 4; ++s) {
    const float* qr = Qg + (size_t)(o0 + s * 16 + l15) * KK;
    qb0[s] = g_frag(qr + l4 * 8);
    qb1[s] = g_frag(qr + 32 + l4 * 8);
  }

  KS ks; VS vs;
  k_load(ks, Kg + (size_t)(ib0 + krow) * KK + kel);
  v_load(vs, Vg + (size_t)(ib0 + vil) * VV + vv0);
  k_write(ks, Kt, krow, kcb);
  v_write(vs, Vt, vil, vv0);
  __syncthreads();

  f32x4 uacc[4];
  float Dacc[4] = {0.f, 0.f, 0.f, 0.f};
#pragma unroll
  for (int s = 0; s < 4; ++s) { f32x4 z = {0.f, 0.f, 0.f, 0.f}; uacc[s] = z; }

  for (int t = 0; t < K1STEPS; ++t) {
    if (t + 1 < K1STEPS) {
      k_load(ks, Kg + (size_t)(ib0 + (t + 1) * IT + krow) * KK + kel);
      v_load(vs, Vg + (size_t)(ib0 + (t + 1) * IT + vil) * VV + vv0);
    }
    // QK: S = K_tile . Q^T ; e = exp ; accumulate D ; write Et[o][i]
    bfrag a0 = lds_frag(Kt, wv * 16 + l15, l4 * 16);
    bfrag a1 = lds_frag(Kt, wv * 16 + l15, 64 + l4 * 16);
#pragma unroll
    for (int s = 0; s < 4; ++s) {
      f32x4 z = {0.f, 0.f, 0.f, 0.f};
      z = __builtin_amdgcn_mfma_f32_16x16x32_bf16(a0, qb0[s], z, 0, 0, 0);
      z = __builtin_amdgcn_mfma_f32_16x16x32_bf16(a1, qb1[s], z, 0, 0, 0);
      f32x4 e;
#pragma unroll
      for (int r = 0; r < 4; ++r) e[r] = exp2f(z[r] * SCALE);
      Dacc[s] += e[0] + e[1] + e[2] + e[3];
      bf16x4 pk;
#pragma unroll
      for (int r = 0; r < 4; ++r) pk[r] = (__bf16)e[r];
      *reinterpret_cast<bf16x4*>(reinterpret_cast<char*>(Et) +
                                 swz(s * 16 + l15, wv * 32 + l4 * 8)) = pk;
    }
    __syncthreads();   // A: Et ready; Kt reads complete
    if (t + 1 < K1STEPS) k_write(ks, Kt, krow, kcb);   // restage K
    // PV: U += V^T . E
    bfrag va0 = lds_frag(Vt, wv * 16 + l15, l4 * 16);
    bfrag va1 = lds_frag(Vt, wv * 16 + l15, 64 + l4 * 16);
#pragma unroll
    for (int s = 0; s < 4; ++s) {
      bfrag e0 = lds_frag(Et, s * 16 + l15, l4 * 16);
      bfrag e1 = lds_frag(Et, s * 16 + l15, 64 + l4 * 16);
      uacc[s] = __builtin_amdgcn_mfma_f32_16x16x32_bf16(va0, e0, uacc[s], 0, 0, 0);
      uacc[s] = __builtin_amdgcn_mfma_f32_16x16x32_bf16(va1, e1, uacc[s], 0, 0, 0);
    }
    __syncthreads();   // B: Vt/Et reads complete; staged Kt visible
    if (t + 1 < K1STEPS) v_write(vs, Vt, vil, vv0);    // restage V
  }

  // partial U -> scratch (v-major [v][o])
#pragma unroll
  for (int s = 0; s < 4; ++s)
#pragma unroll
    for (int r = 0; r < 4; ++r)
      scr[(wv * 16 + l4 * 4 + r) * 64 + s * 16 + l15] = uacc[s][r];

  // partial D -> scratch
#pragma unroll
  for (int s = 0; s < 4; ++s) {
    float d = Dacc[s];
    d += __shfl_xor(d, 16, 64);
    d += __shfl_xor(d, 32, 64);
    if (lane < 16) Red[wv][s * 16 + lane] = d;
  }
  __syncthreads();
  if (tid < 64)
    scr[4096 + tid] = Red[0][tid] + Red[1][tid] + Red[2][tid] + Red[3][tid];
}

// =====================================================================
// K2: reduce 4 chunks -> L2-normalized values + invD (to d_ws)
// grid 256 = (b, o-tile), 512 threads
// =====================================================================
__global__ void __launch_bounds__(512) attn_reduce(
    const float* __restrict__ scratch, float* __restrict__ outV,
    float* __restrict__ invD)
{
  __shared__ float R2[8][64];
  __shared__ float Nn[64];

  const int tid = threadIdx.x;
  const int b   = blockIdx.x & 7;
  const int ot  = blockIdx.x >> 3;
  const float* base = scratch + (size_t)(b * 32 + ot) * 4 * SCR_STRIDE;

  const int ol = tid & 63;    // o within tile
  const int vg = tid >> 6;    // v group 0..7

  float u[8];
#pragma unroll
  for (int j = 0; j < 8; ++j) u[j] = 0.f;
#pragma unroll
  for (int c = 0; c < 4; ++c) {
    const float* p = base + c * SCR_STRIDE;
#pragma unroll
    for (int j = 0; j < 8; ++j) u[j] += p[(vg + 8 * j) * 64 + ol];
  }
  float ssq = 0.f;
#pragma unroll
  for (int j = 0; j < 8; ++j) ssq += u[j] * u[j];
  R2[vg][ol] = ssq;
  __syncthreads();
  if (tid < 64) {
    float n = 0.f;
#pragma unroll
    for (int g = 0; g < 8; ++g) n += R2[g][tid];
    Nn[tid] = 1.f / (sqrtf(n) + 1e-12f);
    float D = 0.f;
#pragma unroll
    for (int c = 0; c < 4; ++c) D += base[c * SCR_STRIDE + 4096 + tid];
    invD[b * NN + ot * 64 + tid] = 1.f / D;
  }
  __syncthreads();
  const float inn = Nn[ol];
  float* vp = outV + (size_t)b * VV * NN + ot * 64 + ol;
#pragma unroll
  for (int j = 0; j < 8; ++j)
    vp[(size_t)(vg + 8 * j) * NN] = u[j] * inn;
}

// =====================================================================
// K3: weights = exp(K.Q^T/8) * invD, 128x128 tile per block.
// A = Q (direct-global wave-private frags), B = K (LDS, shared x4 waves).
// f32x4 NONTEMPORAL stores (weights never re-read; keep L2 for K/Q).
// 16KB LDS, low VGPR (fused per-s epilogue).
// =====================================================================
__global__ void __launch_bounds__(256) attn_weights(
    const float* __restrict__ key, const float* __restrict__ query,
    const float* __restrict__ invD, float* __restrict__ outWall)
{
  __shared__ __align__(16) unsigned short Kt2[128 * 64];

  const int tid  = threadIdx.x;
  const int lane = tid & 63;
  const int wv   = tid >> 6;
  const int l15  = lane & 15;
  const int l4   = lane >> 4;

  const int b    = blockIdx.x & 7;           // batch -> XCD
  const int rest = blockIdx.x >> 3;
  const int it   = rest & 15;                // i-tile (128)
  const int ot   = rest >> 4;                // o-tile (128)

  const float* Kg = key   + (size_t)b * NN * KK;
  const float* Qg = query + (size_t)b * NN * KK;
  float* outW = outWall + (size_t)b * NN * NN;

  // stage K tile: 128 rows x 64 k, 2 threads/row x 32 floats
  {
    const int krow = tid >> 1;
    const int half = (tid & 1);
    KS sA, sB;
    k_load(sA, Kg + (size_t)(it * 128 + krow) * KK + half * 32);
    k_load(sB, Kg + (size_t)(it * 128 + krow) * KK + half * 32 + 16);
    k_write(sA, Kt2, krow, half * 64);
    k_write(sB, Kt2, krow, half * 64 + 32);
  }

  // Q fragments (A-op: o-row = wv*32 + m*16 + l15), direct from global
  bfrag a0[2], a1[2];
#pragma unroll
  for (int m = 0; m < 2; ++m) {
    const float* qr = Qg + (size_t)(ot * 128 + wv * 32 + m * 16 + l15) * KK;
    a0[m] = g_frag(qr + l4 * 8);
    a1[m] = g_frag(qr + 32 + l4 * 8);
  }
  // invD for this lane's 4 consecutive o, both m blocks
  f32x4 id[2];
#pragma unroll
  for (int m = 0; m < 2; ++m)
    id[m] = *reinterpret_cast<const f32x4*>(
        &invD[b * NN + ot * 128 + wv * 32 + m * 16 + l4 * 4]);
  __syncthreads();

#pragma unroll
  for (int s = 0; s < 8; ++s) {
    bfrag b0 = lds_frag(Kt2, s * 16 + l15, l4 * 16);
    bfrag b1 = lds_frag(Kt2, s * 16 + l15, 64 + l4 * 16);
#pragma unroll
    for (int m = 0; m < 2; ++m) {
      f32x4 z = {0.f, 0.f, 0.f, 0.f};
      z = __builtin_amdgcn_mfma_f32_16x16x32_bf16(a0[m], b0, z, 0, 0, 0);
      z = __builtin_amdgcn_mfma_f32_16x16x32_bf16(a1[m], b1, z, 0, 0, 0);
      f32x4 w;
#pragma unroll
      for (int r = 0; r < 4; ++r) w[r] = exp2f(z[r] * SCALE) * id[m][r];
      // weights[i = it*128 + s*16 + l15][o = ot*128 + wv*32 + m*16 + l4*4 ..+3]
      float* wp = outW + (size_t)(it * 128 + s * 16 + l15) * NN +
                  ot * 128 + wv * 32 + m * 16 + l4 * 4;
      __builtin_nontemporal_store(w, reinterpret_cast<f32x4*>(wp));
    }
  }
}

extern "C" void kernel_launch(void* const* d_in, const int* in_sizes, int n_in,
                              void* d_out, int out_size, void* d_ws, size_t ws_size,
                              hipStream_t stream) {
  (void)in_sizes; (void)n_in; (void)ws_size; (void)out_size;
  const float* key   = (const float*)d_in[0];
  const float* query = (const float*)d_in[1];
  const float* value = (const float*)d_in[2];
  float* out  = (float*)d_out;
  float* outV = out;                                  // [B][V][N] values
  float* outW = out + (size_t)NB * VV * NN;           // [B][N][N] weights
  float* invD = (float*)d_ws;                         // 8*2048 floats (64KB)
  float* scratch = outW;                              // K1 partials at head of
                                                      // weights region; K3
                                                      // overwrites after K2.

  attn_pass1 <<<dim3(NB * 32 * 4), dim3(256), 0, stream>>>(key, query, value, scratch);
  attn_reduce<<<dim3(NB * 32),     dim3(512), 0, stream>>>(scratch, outV, invD);
  attn_weights<<<dim3(NB * 16 * 16), dim3(256), 0, stream>>>(key, query, invD, outW);
}

// Round 6
// 79.041 us; speedup vs baseline: 1.5497x; 1.1240x over previous
//
#include <hip/hip_runtime.h>

// Problem constants (fixed by reference)
#define NB 8
#define NN 2048
#define KK 64
#define VV 64
#define SCALE 0.18033688011112043f  // (1/sqrt(64)) * log2(e)

typedef __bf16 bfrag  __attribute__((ext_vector_type(8)));
typedef __bf16 bf16x4 __attribute__((ext_vector_type(4)));
typedef float  f32x4  __attribute__((ext_vector_type(4)));

// LDS byte offset within a tile with 128B rows, XOR-swizzled (G4)
__device__ __forceinline__ int swz(int row, int colByte) {
  return row * 128 + (colByte ^ ((row & 7) << 4));
}

__device__ __forceinline__ bfrag lds_frag(const unsigned short* base, int row, int colByte) {
  return *reinterpret_cast<const bfrag*>(reinterpret_cast<const char*>(base) + swz(row, colByte));
}

// 8 consecutive global fp32 -> bf16 MFMA fragment (v_cvt_pk via plain casts)
__device__ __forceinline__ bfrag g_frag(const float* __restrict__ g) {
  const float4* p = reinterpret_cast<const float4*>(g);
  float4 x = p[0], y = p[1];
  bfrag r;
  r[0] = (__bf16)x.x; r[1] = (__bf16)x.y; r[2] = (__bf16)x.z; r[3] = (__bf16)x.w;
  r[4] = (__bf16)y.x; r[5] = (__bf16)y.y; r[6] = (__bf16)y.z; r[7] = (__bf16)y.w;
  return r;
}

// ---- staging: 16 consecutive fp32 -> 16 bf16 into one LDS row ----
struct KS { float4 f[4]; };
__device__ __forceinline__ void k_load(KS& s, const float* __restrict__ g) {
  const float4* p = reinterpret_cast<const float4*>(g);
  s.f[0] = p[0]; s.f[1] = p[1]; s.f[2] = p[2]; s.f[3] = p[3];
}
__device__ __forceinline__ void k_write(const KS& s, unsigned short* lds, int row, int colByte) {
  const float* f = reinterpret_cast<const float*>(&s.f[0]);
  bfrag a, b;
#pragma unroll
  for (int j = 0; j < 8; ++j) a[j] = (__bf16)f[j];
#pragma unroll
  for (int j = 0; j < 8; ++j) b[j] = (__bf16)f[8 + j];
  *reinterpret_cast<bfrag*>(reinterpret_cast<char*>(lds) + swz(row, colByte)) = a;
  *reinterpret_cast<bfrag*>(reinterpret_cast<char*>(lds) + swz(row, colByte + 16)) = b;
}

// ---- V staging: rows (il, il+1) x 8 v -> transposed Vt[v][i] ----
struct VS { float4 f[4]; };
__device__ __forceinline__ void v_load(VS& s, const float* __restrict__ g) {
  const float4* p = reinterpret_cast<const float4*>(g);
  s.f[0] = p[0]; s.f[1] = p[1];
  const float4* q = reinterpret_cast<const float4*>(g + VV);
  s.f[2] = q[0]; s.f[3] = q[1];
}
__device__ __forceinline__ void v_write(const VS& s, unsigned short* lds, int il, int v0) {
  const float* lo = reinterpret_cast<const float*>(&s.f[0]);
  const float* hi = reinterpret_cast<const float*>(&s.f[2]);
#pragma unroll
  for (int j = 0; j < 8; ++j) {
    __bf16 two[2] = { (__bf16)lo[j], (__bf16)hi[j] };
    *reinterpret_cast<unsigned*>(reinterpret_cast<char*>(lds) + swz(v0 + j, il * 2)) =
        *reinterpret_cast<unsigned*>(two);
  }
}

// =====================================================================
// K1: per (b, o-tile 64, i-chunk 512): partial D[64] + partial U[64][64]
// -> scratch. Q fragments hoisted to registers (direct global); K/V
// single-buffered LDS, 2 barriers/step.
// =====================================================================
#define CHUNK 512
#define IT 64
#define K1STEPS (CHUNK / IT)   // 8
#define SCR_STRIDE 4160        // 64*64 U + 64 D floats per chunk

__global__ void __launch_bounds__(256) attn_pass1(
    const float* __restrict__ key, const float* __restrict__ query,
    const float* __restrict__ value, float* __restrict__ scratch)
{
  __shared__ __align__(16) unsigned short Kt[IT * KK];
  __shared__ __align__(16) unsigned short Vt[VV * IT];
  __shared__ __align__(16) unsigned short Et[64 * IT];
  __shared__ float Red[4][64];

  const int tid  = threadIdx.x;
  const int lane = tid & 63;
  const int wv   = tid >> 6;
  const int l15  = lane & 15;
  const int l4   = lane >> 4;

  const int b    = blockIdx.x & 7;          // batch -> XCD
  const int rest = blockIdx.x >> 3;
  const int ot   = rest & 31;               // o-tile (64)
  const int ci   = rest >> 5;               // i-chunk (512)
  const int o0   = ot * 64;
  const int ib0  = ci * CHUNK;

  const float* Kg = key   + (size_t)b * NN * KK;
  const float* Qg = query + (size_t)b * NN * KK;
  const float* Vg = value + (size_t)b * NN * VV;
  float* scr = scratch + (size_t)((b * 32 + ot) * 4 + ci) * SCR_STRIDE;

  const int krow = tid >> 2;          // 0..63
  const int kel  = (tid & 3) * 16;
  const int kcb  = (tid & 3) * 32;
  const int vil  = (tid & 31) * 2;
  const int vv0  = (tid >> 5) * 8;

  // Q fragments (B-op: o = l15, k = l4*8+j), direct from global
  bfrag qb0[4], qb1[4];
#pragma unroll
  for (int s = 0; s < 4; ++s) {
    const float* qr = Qg + (size_t)(o0 + s * 16 + l15) * KK;
    qb0[s] = g_frag(qr + l4 * 8);
    qb1[s] = g_frag(qr + 32 + l4 * 8);
  }

  KS ks; VS vs;
  k_load(ks, Kg + (size_t)(ib0 + krow) * KK + kel);
  v_load(vs, Vg + (size_t)(ib0 + vil) * VV + vv0);
  k_write(ks, Kt, krow, kcb);
  v_write(vs, Vt, vil, vv0);
  __syncthreads();

  f32x4 uacc[4];
  float Dacc[4] = {0.f, 0.f, 0.f, 0.f};
#pragma unroll
  for (int s = 0; s < 4; ++s) { f32x4 z = {0.f, 0.f, 0.f, 0.f}; uacc[s] = z; }

  for (int t = 0; t < K1STEPS; ++t) {
    if (t + 1 < K1STEPS) {
      k_load(ks, Kg + (size_t)(ib0 + (t + 1) * IT + krow) * KK + kel);
      v_load(vs, Vg + (size_t)(ib0 + (t + 1) * IT + vil) * VV + vv0);
    }
    // QK: S = K_tile . Q^T ; e = exp ; accumulate D ; write Et[o][i]
    bfrag a0 = lds_frag(Kt, wv * 16 + l15, l4 * 16);
    bfrag a1 = lds_frag(Kt, wv * 16 + l15, 64 + l4 * 16);
#pragma unroll
    for (int s = 0; s < 4; ++s) {
      f32x4 z = {0.f, 0.f, 0.f, 0.f};
      z = __builtin_amdgcn_mfma_f32_16x16x32_bf16(a0, qb0[s], z, 0, 0, 0);
      z = __builtin_amdgcn_mfma_f32_16x16x32_bf16(a1, qb1[s], z, 0, 0, 0);
      f32x4 e;
#pragma unroll
      for (int r = 0; r < 4; ++r) e[r] = exp2f(z[r] * SCALE);
      Dacc[s] += e[0] + e[1] + e[2] + e[3];
      bf16x4 pk;
#pragma unroll
      for (int r = 0; r < 4; ++r) pk[r] = (__bf16)e[r];
      *reinterpret_cast<bf16x4*>(reinterpret_cast<char*>(Et) +
                                 swz(s * 16 + l15, wv * 32 + l4 * 8)) = pk;
    }
    __syncthreads();   // A: Et ready; Kt reads complete
    if (t + 1 < K1STEPS) k_write(ks, Kt, krow, kcb);   // restage K
    // PV: U += V^T . E
    bfrag va0 = lds_frag(Vt, wv * 16 + l15, l4 * 16);
    bfrag va1 = lds_frag(Vt, wv * 16 + l15, 64 + l4 * 16);
#pragma unroll
    for (int s = 0; s < 4; ++s) {
      bfrag e0 = lds_frag(Et, s * 16 + l15, l4 * 16);
      bfrag e1 = lds_frag(Et, s * 16 + l15, 64 + l4 * 16);
      uacc[s] = __builtin_amdgcn_mfma_f32_16x16x32_bf16(va0, e0, uacc[s], 0, 0, 0);
      uacc[s] = __builtin_amdgcn_mfma_f32_16x16x32_bf16(va1, e1, uacc[s], 0, 0, 0);
    }
    __syncthreads();   // B: Vt/Et reads complete; staged Kt visible
    if (t + 1 < K1STEPS) v_write(vs, Vt, vil, vv0);    // restage V
  }

  // partial U -> scratch (v-major [v][o])
#pragma unroll
  for (int s = 0; s < 4; ++s)
#pragma unroll
    for (int r = 0; r < 4; ++r)
      scr[(wv * 16 + l4 * 4 + r) * 64 + s * 16 + l15] = uacc[s][r];

  // partial D -> scratch
#pragma unroll
  for (int s = 0; s < 4; ++s) {
    float d = Dacc[s];
    d += __shfl_xor(d, 16, 64);
    d += __shfl_xor(d, 32, 64);
    if (lane < 16) Red[wv][s * 16 + lane] = d;
  }
  __syncthreads();
  if (tid < 64)
    scr[4096 + tid] = Red[0][tid] + Red[1][tid] + Red[2][tid] + Red[3][tid];
}

// =====================================================================
// K2: reduce 4 chunks -> L2-normalized values + invD (to d_ws)
// grid 256 = (b, o-tile), 512 threads
// =====================================================================
__global__ void __launch_bounds__(512) attn_reduce(
    const float* __restrict__ scratch, float* __restrict__ outV,
    float* __restrict__ invD)
{
  __shared__ float R2[8][64];
  __shared__ float Nn[64];

  const int tid = threadIdx.x;
  const int b   = blockIdx.x & 7;
  const int ot  = blockIdx.x >> 3;
  const float* base = scratch + (size_t)(b * 32 + ot) * 4 * SCR_STRIDE;

  const int ol = tid & 63;    // o within tile
  const int vg = tid >> 6;    // v group 0..7

  float u[8];
#pragma unroll
  for (int j = 0; j < 8; ++j) u[j] = 0.f;
#pragma unroll
  for (int c = 0; c < 4; ++c) {
    const float* p = base + c * SCR_STRIDE;
#pragma unroll
    for (int j = 0; j < 8; ++j) u[j] += p[(vg + 8 * j) * 64 + ol];
  }
  float ssq = 0.f;
#pragma unroll
  for (int j = 0; j < 8; ++j) ssq += u[j] * u[j];
  R2[vg][ol] = ssq;
  __syncthreads();
  if (tid < 64) {
    float n = 0.f;
#pragma unroll
    for (int g = 0; g < 8; ++g) n += R2[g][tid];
    Nn[tid] = 1.f / (sqrtf(n) + 1e-12f);
    float D = 0.f;
#pragma unroll
    for (int c = 0; c < 4; ++c) D += base[c * SCR_STRIDE + 4096 + tid];
    invD[b * NN + ot * 64 + tid] = 1.f / D;
  }
  __syncthreads();
  const float inn = Nn[ol];
  float* vp = outV + (size_t)b * VV * NN + ot * 64 + ol;
#pragma unroll
  for (int j = 0; j < 8; ++j)
    vp[(size_t)(vg + 8 * j) * NN] = u[j] * inn;
}

// =====================================================================
// K3: weights = exp(K.Q^T/8) * invD, 128x128 tile per block.
// A = Q (direct-global wave-private frags), B = K (LDS, shared x4 waves).
// Clean MFMA cluster (acc[2][8]) then store-burst epilogue of plain
// (cached, write-back) f32x4 stores along o. 16KB LDS.
// =====================================================================
__global__ void __launch_bounds__(256) attn_weights(
    const float* __restrict__ key, const float* __restrict__ query,
    const float* __restrict__ invD, float* __restrict__ outWall)
{
  __shared__ __align__(16) unsigned short Kt2[128 * 64];

  const int tid  = threadIdx.x;
  const int lane = tid & 63;
  const int wv   = tid >> 6;
  const int l15  = lane & 15;
  const int l4   = lane >> 4;

  const int b    = blockIdx.x & 7;           // batch -> XCD
  const int rest = blockIdx.x >> 3;
  const int it   = rest & 15;                // i-tile (128)
  const int ot   = rest >> 4;                // o-tile (128)

  const float* Kg = key   + (size_t)b * NN * KK;
  const float* Qg = query + (size_t)b * NN * KK;
  float* outW = outWall + (size_t)b * NN * NN;

  // stage K tile: 128 rows x 64 k, 2 threads/row x 32 floats
  {
    const int krow = tid >> 1;
    const int half = (tid & 1);
    KS sA, sB;
    k_load(sA, Kg + (size_t)(it * 128 + krow) * KK + half * 32);
    k_load(sB, Kg + (size_t)(it * 128 + krow) * KK + half * 32 + 16);
    k_write(sA, Kt2, krow, half * 64);
    k_write(sB, Kt2, krow, half * 64 + 32);
  }

  // Q fragments (A-op: o-row = wv*32 + m*16 + l15), direct from global
  bfrag a0[2], a1[2];
#pragma unroll
  for (int m = 0; m < 2; ++m) {
    const float* qr = Qg + (size_t)(ot * 128 + wv * 32 + m * 16 + l15) * KK;
    a0[m] = g_frag(qr + l4 * 8);
    a1[m] = g_frag(qr + 32 + l4 * 8);
  }
  // invD for this lane's 4 consecutive o, both m blocks
  f32x4 id[2];
#pragma unroll
  for (int m = 0; m < 2; ++m)
    id[m] = *reinterpret_cast<const f32x4*>(
        &invD[b * NN + ot * 128 + wv * 32 + m * 16 + l4 * 4]);
  __syncthreads();

  // MFMA cluster: acc[m][s] over the whole tile, no stores interleaved
  f32x4 acc[2][8];
#pragma unroll
  for (int m = 0; m < 2; ++m)
#pragma unroll
    for (int s = 0; s < 8; ++s) { f32x4 z = {0.f, 0.f, 0.f, 0.f}; acc[m][s] = z; }

#pragma unroll
  for (int s = 0; s < 8; ++s) {
    bfrag b0 = lds_frag(Kt2, s * 16 + l15, l4 * 16);
    bfrag b1 = lds_frag(Kt2, s * 16 + l15, 64 + l4 * 16);
#pragma unroll
    for (int m = 0; m < 2; ++m) {
      acc[m][s] = __builtin_amdgcn_mfma_f32_16x16x32_bf16(a0[m], b0, acc[m][s], 0, 0, 0);
      acc[m][s] = __builtin_amdgcn_mfma_f32_16x16x32_bf16(a1[m], b1, acc[m][s], 0, 0, 0);
    }
  }

  // epilogue: exp * invD, f32x4 stores (4 consecutive o per lane)
#pragma unroll
  for (int s = 0; s < 8; ++s)
#pragma unroll
    for (int m = 0; m < 2; ++m) {
      f32x4 w;
#pragma unroll
      for (int r = 0; r < 4; ++r) w[r] = exp2f(acc[m][s][r] * SCALE) * id[m][r];
      // weights[i = it*128 + s*16 + l15][o = ot*128 + wv*32 + m*16 + l4*4 ..+3]
      float* wp = outW + (size_t)(it * 128 + s * 16 + l15) * NN +
                  ot * 128 + wv * 32 + m * 16 + l4 * 4;
      *reinterpret_cast<f32x4*>(wp) = w;
    }
}

extern "C" void kernel_launch(void* const* d_in, const int* in_sizes, int n_in,
                              void* d_out, int out_size, void* d_ws, size_t ws_size,
                              hipStream_t stream) {
  (void)in_sizes; (void)n_in; (void)ws_size; (void)out_size;
  const float* key   = (const float*)d_in[0];
  const float* query = (const float*)d_in[1];
  const float* value = (const float*)d_in[2];
  float* out  = (float*)d_out;
  float* outV = out;                                  // [B][V][N] values
  float* outW = out + (size_t)NB * VV * NN;           // [B][N][N] weights
  float* invD = (float*)d_ws;                         // 8*2048 floats (64KB)
  float* scratch = outW;                              // K1 partials at head of
                                                      // weights region; K3
                                                      // overwrites after K2.

  attn_pass1 <<<dim3(NB * 32 * 4), dim3(256), 0, stream>>>(key, query, value, scratch);
  attn_reduce<<<dim3(NB * 32),     dim3(512), 0, stream>>>(scratch, outV, invD);
  attn_weights<<<dim3(NB * 16 * 16), dim3(256), 0, stream>>>(key, query, invD, outW);
}